// Round 1
// baseline (148.873 us; speedup 1.0000x reference)
//
#include <hip/hip_runtime.h>
#include <hip/hip_bf16.h>

#define NN 8192
#define DK 256
#define NE 131072
#define T128 64                       // 128-row tiles per dim
#define NBLK (T128*(T128+1)/2)        // 2080 upper-triangular tile pairs

typedef __attribute__((ext_vector_type(8))) short bf16x8;
typedef __attribute__((ext_vector_type(4))) float f32x4;

// Device-global scratch (avoids any dependence on ws_size)
__device__ __align__(16) unsigned      g_mask[(size_t)NN*NN/32]; // 8 MB adjacency bitmask
__device__ __align__(16) unsigned short g_bf[(size_t)NN*DK];     // 4 MB bf16 copy of l_enc
__device__ double g_acc;

__device__ __forceinline__ unsigned short f2bf(float f) {
    unsigned u = __float_as_uint(f);
    unsigned r = (u + 0x7FFFu + ((u >> 16) & 1u)) >> 16;   // RNE
    return (unsigned short)r;
}

// ---- Kernel 1: convert l_enc->bf16, zero bitmask + accumulator ----
__global__ void k_prep(const float* __restrict__ x) {
    int i = blockIdx.x * 256 + threadIdx.x;          // 0 .. 524287
    // zero 4 mask words
    uint4 z; z.x = z.y = z.z = z.w = 0u;
    *(uint4*)(&g_mask[(size_t)i * 4]) = z;
    // convert 4 floats -> 4 bf16
    float4 v = ((const float4*)x)[i];
    ushort4 b;
    b.x = f2bf(v.x); b.y = f2bf(v.y); b.z = f2bf(v.z); b.w = f2bf(v.w);
    *(ushort4*)(&g_bf[(size_t)i * 4]) = b;
    if (i == 0) g_acc = 0.0;
}

// ---- Kernel 2: scatter edges into symmetric bitmask ----
__global__ void k_scatter(const long long* __restrict__ ei) {
    int e = blockIdx.x * 256 + threadIdx.x;
    if (e >= NE) return;
    int i = (int)ei[e];
    int j = (int)ei[NE + e];
    atomicOr(&g_mask[(size_t)i * (NN/32) + (j >> 5)], 1u << (j & 31));
    atomicOr(&g_mask[(size_t)j * (NN/32) + (i >> 5)], 1u << (i & 31));
}

// ---- Kernel 3: tiled gram + fused BCE reduction ----
__global__ __launch_bounds__(256, 2) void k_loss() {
    __shared__ __align__(16) unsigned short lA[128 * 128];   // 32 KB (one BK=128 stage)
    __shared__ __align__(16) unsigned short lB[128 * 128];   // 32 KB

    // decode blockIdx -> (ti, tj), ti <= tj
    int rem = blockIdx.x;
    int ti = 0;
    while (rem >= T128 - ti) { rem -= T128 - ti; ++ti; }
    int tj = ti + rem;

    const int tid  = threadIdx.x;
    const int lane = tid & 63;
    const int w    = tid >> 6;       // wave 0..3
    const int wr   = w >> 1;         // wave row 0..1
    const int wc   = w & 1;          // wave col 0..1
    const int lr   = lane & 15;
    const int lq   = lane >> 4;      // 0..3

    f32x4 acc[4][4] = {};

    for (int st = 0; st < 2; ++st) {               // two K-halves of 128
        if (st) __syncthreads();                   // protect LDS overwrite
        // stage A and B tiles (swizzled: 16B slot q -> q ^ (r&7))
        #pragma unroll
        for (int it = 0; it < 8; ++it) {
            int c = tid + it * 256;                // 0..2047
            int r = c >> 4, q = c & 15;
            int slot = q ^ (r & 7);
            uint4 va = *(const uint4*)(&g_bf[(size_t)(ti*128 + r) * DK + st*128 + q*8]);
            *(uint4*)((char*)lA + r * 256 + slot * 16) = va;
            uint4 vb = *(const uint4*)(&g_bf[(size_t)(tj*128 + r) * DK + st*128 + q*8]);
            *(uint4*)((char*)lB + r * 256 + slot * 16) = vb;
        }
        __syncthreads();

        #pragma unroll
        for (int ks = 0; ks < 4; ++ks) {           // k-steps of 32 within this stage
            bf16x8 fa[4], fb[4];
            #pragma unroll
            for (int fm = 0; fm < 4; ++fm) {
                int ra = wr * 64 + fm * 16 + lr;
                int sa = (ks * 4 + lq) ^ (lr & 7); // ra&7 == lr&7 (base mult of 16)
                fa[fm] = *(const bf16x8*)((const char*)lA + ra * 256 + sa * 16);
                int rb = wc * 64 + fm * 16 + lr;
                fb[fm] = *(const bf16x8*)((const char*)lB + rb * 256 + sa * 16);
            }
            #pragma unroll
            for (int fm = 0; fm < 4; ++fm)
                #pragma unroll
                for (int fn = 0; fn < 4; ++fn)
                    acc[fm][fn] = __builtin_amdgcn_mfma_f32_16x16x32_bf16(
                        fa[fm], fb[fn], acc[fm][fn], 0, 0, 0);
        }
    }

    // ---- fused epilogue: emulate fp32 sigmoid/log exactly enough ----
    float tsum = 0.0f;
    const int R0 = ti * 128 + wr * 64;
    const int C0 = tj * 128 + wc * 64;
    #pragma unroll
    for (int fm = 0; fm < 4; ++fm) {
        #pragma unroll
        for (int fn = 0; fn < 4; ++fn) {
            int colg = C0 + fn * 16 + lr;
            int wordcol = colg >> 5;
            #pragma unroll
            for (int r2 = 0; r2 < 4; ++r2) {
                int rowg = R0 + fm * 16 + lq * 4 + r2;
                float s = acc[fm][fn][r2];
                unsigned wbits = g_mask[(size_t)rowg * (NN/32) + wordcol];
                int bit = (wbits >> (colg & 31)) & 1;
                float e   = __expf(-s);
                float res = 1.0f / (1.0f + e);     // fp32 rounding: res==1 once e < 2^-24
                float term = fminf(-__logf(1.0f - res), 100.0f);   // a=0 branch
                if (bit)          term = fminf(-__logf(res), 100.0f); // a=1 branch
                if (rowg == colg) term = bit ? 100.0f : 0.0f;         // masked diagonal
                tsum += term;
            }
        }
    }
    // wave reduce then one f64 atomic per wave
    #pragma unroll
    for (int off = 32; off; off >>= 1) tsum += __shfl_down(tsum, off);
    if (lane == 0) {
        float wgt = (ti == tj) ? 1.0f : 2.0f;
        atomicAdd(&g_acc, (double)(tsum * wgt));
    }
}

// ---- Kernel 4: finalize ----
__global__ void k_final(float* __restrict__ out) {
    out[0] = (float)(g_acc * (1.0 / ((double)NN * (double)NN)));
}

extern "C" void kernel_launch(void* const* d_in, const int* in_sizes, int n_in,
                              void* d_out, int out_size, void* d_ws, size_t ws_size,
                              hipStream_t stream) {
    const float* l_enc = (const float*)d_in[0];
    const long long* ei = (const long long*)d_in[1];
    float* out = (float*)d_out;

    k_prep<<<2048, 256, 0, stream>>>(l_enc);            // 2048*256*4 = 2M elems/words
    k_scatter<<<NE / 256, 256, 0, stream>>>(ei);
    k_loss<<<NBLK, 256, 0, stream>>>();
    k_final<<<1, 64, 0, stream>>>(out);
}